// Round 3
// baseline (4730.533 us; speedup 1.0000x reference)
//
#include <hip/hip_runtime.h>
#include <hip/hip_bf16.h>
#include <cstddef>
#include <cstdint>

// EdgeLevelRNN: B=1024, T=64, N=128, E=H=NH=256, HEADS=4, DH=64, F=1, L=2
// Phase A: k/v proj GEMM, gi0 GEMM, weight converts + recurrent-weight packing.
// Phase B (serial): seq3_kernel, 64 blocks x 512 thr, 16 batches/block.
//   Weights pre-packed per (wave, tile, k-step) so each wave streams its
//   step's weights CONTIGUOUSLY straight into VGPRs (8-deep rotating b128
//   buffers, issue 6 ahead). LDS holds only h-state + gi0 stage (DMA'd).
// Phase C (parallel): q GEMM, attention, fused Wo/Wc/W1/W2 chain.

#define B_  1024
#define T_  64
#define N_  128

typedef __attribute__((ext_vector_type(8))) short s16x8;
typedef __attribute__((ext_vector_type(4))) float f32x4;

__device__ __forceinline__ unsigned short f2b(float f) {
  unsigned int u = __float_as_uint(f);
  u += 0x7FFFu + ((u >> 16) & 1u);          // RNE
  return (unsigned short)(u >> 16);
}
__device__ __forceinline__ float b2f(unsigned short s){ return __uint_as_float(((unsigned int)s) << 16); }
__device__ __forceinline__ float sigmoidf_(float x){ return 1.0f / (1.0f + __expf(-x)); }
__device__ __forceinline__ float tanhf_(float x){
  float t = __expf(-2.0f * fabsf(x));
  float r = (1.0f - t) / (1.0f + t);
  return x >= 0.0f ? r : -r;
}
__device__ __forceinline__ void gld_lds16(const void* g, void* l) {
  __builtin_amdgcn_global_load_lds(
      (const __attribute__((address_space(1))) void*)g,
      (__attribute__((address_space(3))) void*)l, 16, 0, 0);
}

__global__ void cvt_bf16(const float* __restrict__ s, unsigned short* __restrict__ d, int n) {
  int i = blockIdx.x * blockDim.x + threadIdx.x;
  if (i < n) d[i] = f2b(s[i]);
}

// Pack Whh0 into per-(wave,tile,kc,lane) stream order for seq3.
// dst[d]: d = ((w*6 + j)*8 + kc)*512 + l*8 + e
//   row = (j>>1)*256 + w*32 + (j&1)*16 + (l&15); col = kc*32 + (l>>4)*8 + e
__global__ void pack_w1(const float* __restrict__ Whh0, unsigned short* __restrict__ dst) {
  int d = blockIdx.x * 256 + threadIdx.x;            // 196608
  int e = d & 7, l = (d >> 3) & 63, blk = d >> 9;
  int kc = blk & 7, tj = blk >> 3;                   // tj: 0..47
  int j = tj % 6, w = tj / 6;
  int row = (j >> 1) * 256 + w * 32 + (j & 1) * 16 + (l & 15);
  int colk = kc * 32 + (l >> 4) * 8 + e;
  dst[d] = f2b(Whh0[(size_t)row * 256 + colk]);
}
// Pack [Wih1 (j<6) ; Whh1 (j>=6)] similarly: d = ((w*12 + j)*8 + kc)*512 + l*8 + e
__global__ void pack_w2(const float* __restrict__ Wih1, const float* __restrict__ Whh1,
                        unsigned short* __restrict__ dst) {
  int d = blockIdx.x * 256 + threadIdx.x;            // 393216
  int e = d & 7, l = (d >> 3) & 63, blk = d >> 9;
  int kc = blk & 7, tj = blk >> 3;                   // tj: 0..95
  int j = tj % 12, w = tj / 12;
  int jj = (j < 6) ? j : j - 6;
  int row = (jj >> 1) * 256 + w * 32 + (jj & 1) * 16 + (l & 15);
  int colk = kc * 32 + (l >> 4) * 8 + e;
  const float* src = (j < 6) ? Wih1 : Whh1;
  dst[d] = f2b(src[(size_t)row * 256 + colk]);
}

#define LDA 264   // 256 + 8 pad (bf16 elems)
#define LDB 40    // 32 + 8 pad

// PK1: C[m, 0:512] = phn[m,:] @ [Wk;Wv]^T + [bk;bv]; split to k_all / v_all (bf16)
__global__ __launch_bounds__(256) void kv_gemm(
    const float* __restrict__ phn,
    const float* __restrict__ Wk, const float* __restrict__ Wv,
    const float* __restrict__ bk, const float* __restrict__ bv,
    unsigned short* __restrict__ k_all, unsigned short* __restrict__ v_all)
{
  __shared__ __align__(16) unsigned short Alds[64 * LDA];
  __shared__ __align__(16) unsigned short Blds[256 * LDB];
  const int tid = threadIdx.x;
  const int m0 = blockIdx.x * 64;
  const int n0 = blockIdx.y * 256;
  #pragma unroll
  for (int p = 0; p < 16; ++p) {
    int q = p * 256 + tid;
    int row = q >> 6, kq = q & 63;
    float4 f = *(const float4*)&phn[(size_t)(m0 + row) * 256 + (size_t)kq * 4];
    ushort4 h; h.x = f2b(f.x); h.y = f2b(f.y); h.z = f2b(f.z); h.w = f2b(f.w);
    *(ushort4*)&Alds[row * LDA + kq * 4] = h;
  }
  const int wave = tid >> 6, lane = tid & 63;
  const int lr = lane & 15, lk = (lane >> 4) * 8;
  f32x4 acc[16];
  #pragma unroll
  for (int t = 0; t < 16; ++t) {
    int j = n0 + t * 16 + lr;
    float bz = (j < 256) ? bk[j] : bv[j - 256];
    acc[t][0] = bz; acc[t][1] = bz; acc[t][2] = bz; acc[t][3] = bz;
  }
  for (int kc = 0; kc < 8; ++kc) {
    __syncthreads();
    #pragma unroll
    for (int p = 0; p < 8; ++p) {
      int j = p * 32 + (tid >> 3);
      int jg = n0 + j;
      const float* wrow = (jg < 256) ? &Wk[(size_t)jg * 256] : &Wv[(size_t)(jg - 256) * 256];
      float4 f = *(const float4*)&wrow[kc * 32 + (tid & 7) * 4];
      ushort4 h; h.x = f2b(f.x); h.y = f2b(f.y); h.z = f2b(f.z); h.w = f2b(f.w);
      *(ushort4*)&Blds[j * LDB + (tid & 7) * 4] = h;
    }
    __syncthreads();
    s16x8 a = *(const s16x8*)&Alds[(wave * 16 + lr) * LDA + kc * 32 + lk];
    #pragma unroll
    for (int t = 0; t < 16; ++t) {
      s16x8 b = *(const s16x8*)&Blds[(t * 16 + lr) * LDB + lk];
      acc[t] = __builtin_amdgcn_mfma_f32_16x16x32_bf16(a, b, acc[t], 0, 0, 0);
    }
  }
  const int rbase = m0 + wave * 16 + (lane >> 4) * 4;
  #pragma unroll
  for (int t = 0; t < 16; ++t) {
    int j = n0 + t * 16 + lr;
    #pragma unroll
    for (int i = 0; i < 4; ++i) {
      size_t m = (size_t)(rbase + i);
      unsigned short hv = f2b(acc[t][i]);
      if (j < 256) k_all[m * 256 + j] = hv;
      else         v_all[m * 256 + (j - 256)] = hv;
    }
  }
}

// PK2: gi0[t][b][f0:f0+256] = relu(x[m]*W_in + b_in) @ Wih0^T + bih0 (bf16)
__global__ __launch_bounds__(256) void gi0_gemm(
    const float* __restrict__ x, const float* __restrict__ W_in, const float* __restrict__ b_in,
    const float* __restrict__ Wih0, const float* __restrict__ bih0,
    unsigned short* __restrict__ gi0)
{
  __shared__ __align__(16) unsigned short Alds[64 * LDA];
  __shared__ __align__(16) unsigned short Blds[256 * LDB];
  const int tid = threadIdx.x;
  const int m0 = blockIdx.x * 64;
  const int f0 = blockIdx.y * 256;
  float win = W_in[tid], bin = b_in[tid];
  for (int p = 0; p < 64; ++p) {
    float e = fmaxf(fmaf(x[m0 + p], win, bin), 0.0f);
    Alds[p * LDA + tid] = f2b(e);
  }
  const int wave = tid >> 6, lane = tid & 63;
  const int lr = lane & 15, lk = (lane >> 4) * 8;
  f32x4 acc[16];
  #pragma unroll
  for (int t = 0; t < 16; ++t) {
    float bz = bih0[f0 + t * 16 + lr];
    acc[t][0] = bz; acc[t][1] = bz; acc[t][2] = bz; acc[t][3] = bz;
  }
  for (int kc = 0; kc < 8; ++kc) {
    __syncthreads();
    #pragma unroll
    for (int p = 0; p < 8; ++p) {
      int j = p * 32 + (tid >> 3);
      const float* wrow = &Wih0[(size_t)(f0 + j) * 256];
      float4 f = *(const float4*)&wrow[kc * 32 + (tid & 7) * 4];
      ushort4 h; h.x = f2b(f.x); h.y = f2b(f.y); h.z = f2b(f.z); h.w = f2b(f.w);
      *(ushort4*)&Blds[j * LDB + (tid & 7) * 4] = h;
    }
    __syncthreads();
    s16x8 a = *(const s16x8*)&Alds[(wave * 16 + lr) * LDA + kc * 32 + lk];
    #pragma unroll
    for (int t = 0; t < 16; ++t) {
      s16x8 b = *(const s16x8*)&Blds[(t * 16 + lr) * LDB + lk];
      acc[t] = __builtin_amdgcn_mfma_f32_16x16x32_bf16(a, b, acc[t], 0, 0, 0);
    }
  }
  const int rbase = m0 + wave * 16 + (lane >> 4) * 4;
  #pragma unroll
  for (int t = 0; t < 16; ++t) {
    int f = f0 + t * 16 + lr;
    #pragma unroll
    for (int i = 0; i < 4; ++i) {
      int m = rbase + i;                       // m = b*64 + t
      gi0[((size_t)(m & 63) * 1024 + (m >> 6)) * 768 + f] = f2b(acc[t][i]);
    }
  }
}

// ---------------- Phase B: sequential GRU core, weights -> VGPR stream ----------------
__global__ __launch_bounds__(512) void seq3_kernel(
    const unsigned short* __restrict__ gi0,     // [T][B][768]
    const float* __restrict__ h0_init,          // [2][B][256]
    const unsigned short* __restrict__ wpk1,    // [w][6][8][512]
    const float* __restrict__ bhh0,
    const unsigned short* __restrict__ wpk2,    // [w][12][8][512]
    const float* __restrict__ bih1, const float* __restrict__ bhh1,
    unsigned short* __restrict__ h1_all)        // [B][T][256]
{
  __shared__ __align__(16) unsigned short h0b[16][264];
  __shared__ __align__(16) unsigned short h1b[16][264];
  __shared__ __align__(16) unsigned short gi0s[16 * 768];   // 24KB, linear (DMA dest)

  const int tid = threadIdx.x;
  const int w = tid >> 6, lane = tid & 63;
  const int col = lane & 15, kg = lane >> 4;
  const int b0 = blockIdx.x * 16;

  // init state: lane owns (batch kg*4+i, feature w*32+sub*16+col)
  float hp0[8], hp1[8];
  #pragma unroll
  for (int sub = 0; sub < 2; ++sub)
    #pragma unroll
    for (int i = 0; i < 4; ++i) {
      int bt = kg * 4 + i, fl = w * 32 + sub * 16 + col;
      float v0 = h0_init[(size_t)(b0 + bt) * 256 + fl];
      float v1 = h0_init[(size_t)(B_ * 256) + (size_t)(b0 + bt) * 256 + fl];
      hp0[sub * 4 + i] = v0; hp1[sub * 4 + i] = v1;
      h0b[bt][fl] = f2b(v0); h1b[bt][fl] = f2b(v1);
    }
  float bb0[6], bb1[12];
  #pragma unroll
  for (int j = 0; j < 6; ++j) {
    int f = (j >> 1) * 256 + w * 32 + (j & 1) * 16 + col;
    bb0[j] = bhh0[f];
    bb1[j] = bih1[f];
    bb1[6 + j] = bhh1[f];
  }
  __syncthreads();

  const unsigned short* w1base = wpk1 + (size_t)w * 24576 + (size_t)lane * 8;
  const unsigned short* w2base = wpk2 + (size_t)w * 49152 + (size_t)lane * 8;

  s16x8 Wr[8];

  #pragma unroll 1
  for (int t = 0; t < T_; ++t) {
    // --- stage gi0 tile (16 rows x 768) into LDS via DMA: 3 chunks/wave ---
    {
      const unsigned short* gsrc = gi0 + ((size_t)t * 1024 + b0) * 768;
      #pragma unroll
      for (int c = 0; c < 3; ++c)
        gld_lds16(gsrc + (size_t)(w * 3 + c) * 512 + (size_t)lane * 8,
                  &gi0s[(w * 3 + c) * 512]);
    }
    __builtin_amdgcn_sched_barrier(0);
    // S1 weight prologue (6 ahead)
    #pragma unroll
    for (int p = 0; p < 6; ++p)
      Wr[p] = *(const s16x8*)(w1base + (size_t)p * 512);
    // A-frags (old state) — must be read by ALL waves before anyone rewrites
    s16x8 h0o[8], h1o[8];
    #pragma unroll
    for (int kc = 0; kc < 8; ++kc) {
      h0o[kc] = *(const s16x8*)&h0b[col][kc * 32 + kg * 8];
      h1o[kc] = *(const s16x8*)&h1b[col][kc * 32 + kg * 8];
    }
    // ensure this wave's gi0 DMA (oldest 3-4 vmem ops) completed, then publish
    asm volatile("s_waitcnt vmcnt(6)" ::: "memory");
    __syncthreads();                                   // (a)

    // ---- S1: gh0 = h0 @ Whh0^T + bhh0 (48 MFMA), fused GRU0 ----
    f32x4 acc[6];
    #pragma unroll
    for (int j = 0; j < 6; ++j) { float bz = bb0[j]; acc[j][0]=bz; acc[j][1]=bz; acc[j][2]=bz; acc[j][3]=bz; }
    #pragma unroll
    for (int j = 0; j < 6; ++j) {
      #pragma unroll
      for (int kc = 0; kc < 8; ++kc) {
        const int g = j * 8 + kc;
        if (g + 6 < 48) Wr[(g + 6) & 7] = *(const s16x8*)(w1base + (size_t)(g + 6) * 512);
        else            Wr[(g + 6) & 7] = *(const s16x8*)(w2base + (size_t)(g + 6 - 48) * 512);
        acc[j] = __builtin_amdgcn_mfma_f32_16x16x32_bf16(h0o[kc], Wr[g & 7], acc[j], 0, 0, 0);
      }
    }
    // GRU0 elementwise (all 512 lanes, 8 outputs each)
    #pragma unroll
    for (int sub = 0; sub < 2; ++sub) {
      const int fl = w * 32 + sub * 16 + col;
      #pragma unroll
      for (int i = 0; i < 4; ++i) {
        const int bt = kg * 4 + i;
        float ir  = b2f(gi0s[bt * 768 + fl]);
        float iz  = b2f(gi0s[bt * 768 + 256 + fl]);
        float in_ = b2f(gi0s[bt * 768 + 512 + fl]);
        float r = sigmoidf_(ir + acc[0 + sub][i]);
        float z = sigmoidf_(iz + acc[2 + sub][i]);
        float n = tanhf_(in_ + r * acc[4 + sub][i]);
        float hn = (1.0f - z) * n + z * hp0[sub * 4 + i];
        hp0[sub * 4 + i] = hn;
        h0b[bt][fl] = f2b(hn);
      }
    }
    __syncthreads();                                   // (b)

    // ---- S2: gi1 = h0n @ Wih1^T ; gh1 = h1 @ Whh1^T (96 MFMA), fused GRU1 ----
    s16x8 h0n[8];
    #pragma unroll
    for (int kc = 0; kc < 8; ++kc)
      h0n[kc] = *(const s16x8*)&h0b[col][kc * 32 + kg * 8];
    f32x4 acc2[12];
    #pragma unroll
    for (int j = 0; j < 12; ++j) { float bz = bb1[j]; acc2[j][0]=bz; acc2[j][1]=bz; acc2[j][2]=bz; acc2[j][3]=bz; }
    #pragma unroll
    for (int j = 0; j < 12; ++j) {
      #pragma unroll
      for (int kc = 0; kc < 8; ++kc) {
        const int g = j * 8 + kc;
        if (g + 6 < 96) Wr[(g + 6) & 7] = *(const s16x8*)(w2base + (size_t)(g + 6) * 512);
        s16x8 af = (j < 6) ? h0n[kc] : h1o[kc];
        acc2[j] = __builtin_amdgcn_mfma_f32_16x16x32_bf16(af, Wr[g & 7], acc2[j], 0, 0, 0);
      }
    }
    // GRU1 elementwise
    #pragma unroll
    for (int sub = 0; sub < 2; ++sub) {
      const int fl = w * 32 + sub * 16 + col;
      #pragma unroll
      for (int i = 0; i < 4; ++i) {
        const int bt = kg * 4 + i;
        float r = sigmoidf_(acc2[0 + sub][i] + acc2[6 + sub][i]);
        float z = sigmoidf_(acc2[2 + sub][i] + acc2[8 + sub][i]);
        float n = tanhf_(acc2[4 + sub][i] + r * acc2[10 + sub][i]);
        float hn = (1.0f - z) * n + z * hp1[sub * 4 + i];
        hp1[sub * 4 + i] = hn;
        h1b[bt][fl] = f2b(hn);
      }
    }
    __syncthreads();                                   // (c)

    // h1b -> h1_all, coalesced: wave w stores rows 2w, 2w+1 (512B each)
    {
      const int row = 2 * w + (lane >> 5), c16 = lane & 31;
      s16x8 vv = *(const s16x8*)&h1b[row][c16 * 8];
      *(s16x8*)&h1_all[((size_t)(b0 + row) * T_ + t) * 256 + c16 * 8] = vv;
    }
  }
}

// ---------------- Phase C ----------------
// C1: q_all = (h1_all @ Wq^T + bq) * 0.125   (bf16)
__global__ __launch_bounds__(256) void q_gemm(
    const unsigned short* __restrict__ h1_all,
    const unsigned short* __restrict__ w_q, const float* __restrict__ bq,
    unsigned short* __restrict__ q_all)
{
  __shared__ __align__(16) unsigned short A[64][264];
  const int tid = threadIdx.x;
  const int m0 = blockIdx.x * 64;
  #pragma unroll
  for (int p = 0; p < 8; ++p) {
    int idx = p * 256 + tid;
    int row = idx >> 5, c8 = idx & 31;
    *(uint4*)&A[row][c8 * 8] = *(const uint4*)&h1_all[(size_t)(m0 + row) * 256 + c8 * 8];
  }
  __syncthreads();
  const int wv = tid >> 6, lane = tid & 63;
  const int col = lane & 15, kg = lane >> 4;
  f32x4 acc[16];
  #pragma unroll
  for (int ct = 0; ct < 16; ++ct) {
    float bz = bq[ct * 16 + col];
    acc[ct][0]=bz; acc[ct][1]=bz; acc[ct][2]=bz; acc[ct][3]=bz;
  }
  #pragma unroll
  for (int kc = 0; kc < 8; ++kc) {
    s16x8 af = *(const s16x8*)&A[wv * 16 + col][kc * 32 + kg * 8];
    #pragma unroll
    for (int ct = 0; ct < 16; ++ct) {
      s16x8 bf = *(const s16x8*)&w_q[(size_t)(ct * 16 + col) * 256 + kc * 32 + kg * 8];
      acc[ct] = __builtin_amdgcn_mfma_f32_16x16x32_bf16(af, bf, acc[ct], 0, 0, 0);
    }
  }
  const int r0 = m0 + wv * 16 + kg * 4;
  #pragma unroll
  for (int ct = 0; ct < 16; ++ct) {
    int j = ct * 16 + col;
    #pragma unroll
    for (int i = 0; i < 4; ++i)
      q_all[(size_t)(r0 + i) * 256 + j] = f2b(acc[ct][i] * 0.125f);
  }
}

// C2: attention per (b): scores = q.k, softmax(+mask), ctx = a.v  -> ctx_all
__global__ __launch_bounds__(256) void attn_kernel(
    const unsigned short* __restrict__ q_all,
    const unsigned short* __restrict__ k_all,
    const unsigned short* __restrict__ v_all,
    const unsigned char* __restrict__ amask,
    unsigned short* __restrict__ ctx_all)
{
  __shared__ __align__(16) unsigned short qh[64][72];
  __shared__ __align__(16) unsigned short kh[128][72];
  __shared__ __align__(16) unsigned short vT[64][136];
  __shared__ __align__(16) unsigned short P[64][136];
  const int b = blockIdx.x;
  const int tid = threadIdx.x;
  const int wv = tid >> 6, lane = tid & 63;
  const int col = lane & 15, kg = lane >> 4;
  bool mk[8];
  #pragma unroll
  for (int nt = 0; nt < 8; ++nt) mk[nt] = amask[(size_t)b * 128 + nt * 16 + col] != 0;

  #pragma unroll 1
  for (int h = 0; h < 4; ++h) {
    #pragma unroll
    for (int p = 0; p < 2; ++p) {
      int idx = p * 256 + tid, row = idx >> 3, c8 = idx & 7;
      *(uint4*)&qh[row][c8 * 8] = *(const uint4*)&q_all[((size_t)b * 64 + row) * 256 + h * 64 + c8 * 8];
    }
    #pragma unroll
    for (int p = 0; p < 4; ++p) {
      int idx = p * 256 + tid, row = idx >> 3, c8 = idx & 7;
      *(uint4*)&kh[row][c8 * 8] = *(const uint4*)&k_all[((size_t)b * 128 + row) * 256 + h * 64 + c8 * 8];
    }
    #pragma unroll
    for (int rep = 0; rep < 32; ++rep) {
      int e = rep * 256 + tid;
      int n = e >> 6, d = e & 63;
      vT[d][n] = v_all[((size_t)b * 128 + n) * 256 + h * 64 + d];
    }
    __syncthreads();

    s16x8 aq0 = *(const s16x8*)&qh[wv * 16 + col][kg * 8];
    s16x8 aq1 = *(const s16x8*)&qh[wv * 16 + col][32 + kg * 8];
    f32x4 s[8];
    #pragma unroll
    for (int nt = 0; nt < 8; ++nt) {
      f32x4 z = {0.f, 0.f, 0.f, 0.f};
      s16x8 bk0 = *(const s16x8*)&kh[nt * 16 + col][kg * 8];
      s16x8 bk1 = *(const s16x8*)&kh[nt * 16 + col][32 + kg * 8];
      z = __builtin_amdgcn_mfma_f32_16x16x32_bf16(aq0, bk0, z, 0, 0, 0);
      z = __builtin_amdgcn_mfma_f32_16x16x32_bf16(aq1, bk1, z, 0, 0, 0);
      s[nt] = z;
    }
    #pragma unroll
    for (int nt = 0; nt < 8; ++nt)
      if (mk[nt]) { s[nt][0] = -1e9f; s[nt][1] = -1e9f; s[nt][2] = -1e9f; s[nt][3] = -1e9f; }
    f32x4 mx = s[0];
    #pragma unroll
    for (int nt = 1; nt < 8; ++nt)
      #pragma unroll
      for (int i = 0; i < 4; ++i) mx[i] = fmaxf(mx[i], s[nt][i]);
    #pragma unroll
    for (int i = 0; i < 4; ++i) {
      float m = mx[i];
      m = fmaxf(m, __shfl_xor(m, 1)); m = fmaxf(m, __shfl_xor(m, 2));
      m = fmaxf(m, __shfl_xor(m, 4)); m = fmaxf(m, __shfl_xor(m, 8));
      mx[i] = m;
    }
    f32x4 sm = {0.f, 0.f, 0.f, 0.f};
    #pragma unroll
    for (int nt = 0; nt < 8; ++nt)
      #pragma unroll
      for (int i = 0; i < 4; ++i) { s[nt][i] = __expf(s[nt][i] - mx[i]); sm[i] += s[nt][i]; }
    #pragma unroll
    for (int i = 0; i < 4; ++i) {
      float t2 = sm[i];
      t2 += __shfl_xor(t2, 1); t2 += __shfl_xor(t2, 2);
      t2 += __shfl_xor(t2, 4); t2 += __shfl_xor(t2, 8);
      sm[i] = 1.0f / t2;
    }
    #pragma unroll
    for (int nt = 0; nt < 8; ++nt)
      #pragma unroll
      for (int i = 0; i < 4; ++i)
        P[wv * 16 + kg * 4 + i][nt * 16 + col] = f2b(s[nt][i] * sm[i]);
    __syncthreads();

    f32x4 c4[4];
    #pragma unroll
    for (int dt = 0; dt < 4; ++dt) { c4[dt][0]=0.f; c4[dt][1]=0.f; c4[dt][2]=0.f; c4[dt][3]=0.f; }
    #pragma unroll
    for (int kc = 0; kc < 4; ++kc) {
      s16x8 ap = *(const s16x8*)&P[wv * 16 + col][kc * 32 + kg * 8];
      #pragma unroll
      for (int dt = 0; dt < 4; ++dt) {
        s16x8 bv_ = *(const s16x8*)&vT[dt * 16 + col][kc * 32 + kg * 8];
        c4[dt] = __builtin_amdgcn_mfma_f32_16x16x32_bf16(ap, bv_, c4[dt], 0, 0, 0);
      }
    }
    #pragma unroll
    for (int dt = 0; dt < 4; ++dt) {
      int d = h * 64 + dt * 16 + col;
      #pragma unroll
      for (int i = 0; i < 4; ++i)
        ctx_all[((size_t)b * 64 + wv * 16 + kg * 4 + i) * 256 + d] = f2b(c4[dt][i]);
    }
    __syncthreads();
  }
}

// C3: o = ctx@Wo^T+bo; comb = relu([h1,o]@Wc^T+bc); w1 = relu(comb@W1^T+b1);
//     out = sigmoid(w1.W2 + b2)
__global__ __launch_bounds__(256) void out_chain(
    const unsigned short* __restrict__ h1_all,
    const unsigned short* __restrict__ ctx_all,
    const unsigned short* __restrict__ w_o, const float* __restrict__ bo,
    const unsigned short* __restrict__ w_c, const float* __restrict__ bc,
    const unsigned short* __restrict__ w_1, const float* __restrict__ b1,
    const float* __restrict__ W2, const float* __restrict__ b2,
    float* __restrict__ out)
{
  __shared__ __align__(16) unsigned short BufA[64][264];
  __shared__ __align__(16) unsigned short BufB[64][264];
  const int b = blockIdx.x;
  const int tid = threadIdx.x;
  const int wv = tid >> 6, lane = tid & 63;
  const int col = lane & 15, kg = lane >> 4;
  const size_t mbase = (size_t)b * 64;
  #pragma unroll
  for (int p = 0; p < 8; ++p) {
    int idx = p * 256 + tid, row = idx >> 5, c8 = idx & 31;
    *(uint4*)&BufA[row][c8 * 8] = *(const uint4*)&h1_all[(mbase + row) * 256 + c8 * 8];
    *(uint4*)&BufB[row][c8 * 8] = *(const uint4*)&ctx_all[(mbase + row) * 256 + c8 * 8];
  }
  __syncthreads();
  f32x4 acc[16];

  // step1: o = ctx @ Wo^T + bo
  #pragma unroll
  for (int ct = 0; ct < 16; ++ct) { float bz = bo[ct*16+col]; acc[ct][0]=bz; acc[ct][1]=bz; acc[ct][2]=bz; acc[ct][3]=bz; }
  #pragma unroll
  for (int kc = 0; kc < 8; ++kc) {
    s16x8 af = *(const s16x8*)&BufB[wv * 16 + col][kc * 32 + kg * 8];
    #pragma unroll
    for (int ct = 0; ct < 16; ++ct) {
      s16x8 bf = *(const s16x8*)&w_o[(size_t)(ct * 16 + col) * 256 + kc * 32 + kg * 8];
      acc[ct] = __builtin_amdgcn_mfma_f32_16x16x32_bf16(af, bf, acc[ct], 0, 0, 0);
    }
  }
  __syncthreads();
  #pragma unroll
  for (int ct = 0; ct < 16; ++ct)
    #pragma unroll
    for (int i = 0; i < 4; ++i)
      BufB[wv * 16 + kg * 4 + i][ct * 16 + col] = f2b(acc[ct][i]);
  __syncthreads();

  // step2: comb = relu(h1@Wc[:,:256]^T + o@Wc[:,256:]^T + bc)
  #pragma unroll
  for (int ct = 0; ct < 16; ++ct) { float bz = bc[ct*16+col]; acc[ct][0]=bz; acc[ct][1]=bz; acc[ct][2]=bz; acc[ct][3]=bz; }
  #pragma unroll
  for (int kc = 0; kc < 16; ++kc) {
    s16x8 af;
    if (kc < 8) af = *(const s16x8*)&BufA[wv * 16 + col][kc * 32 + kg * 8];
    else        af = *(const s16x8*)&BufB[wv * 16 + col][(kc - 8) * 32 + kg * 8];
    #pragma unroll
    for (int ct = 0; ct < 16; ++ct) {
      s16x8 bf = *(const s16x8*)&w_c[(size_t)(ct * 16 + col) * 512 + kc * 32 + kg * 8];
      acc[ct] = __builtin_amdgcn_mfma_f32_16x16x32_bf16(af, bf, acc[ct], 0, 0, 0);
    }
  }
  __syncthreads();
  #pragma unroll
  for (int ct = 0; ct < 16; ++ct)
    #pragma unroll
    for (int i = 0; i < 4; ++i)
      BufB[wv * 16 + kg * 4 + i][ct * 16 + col] = f2b(fmaxf(acc[ct][i], 0.0f));
  __syncthreads();

  // step3: w1 = relu(comb @ W1^T + b1)
  #pragma unroll
  for (int ct = 0; ct < 16; ++ct) { float bz = b1[ct*16+col]; acc[ct][0]=bz; acc[ct][1]=bz; acc[ct][2]=bz; acc[ct][3]=bz; }
  #pragma unroll
  for (int kc = 0; kc < 8; ++kc) {
    s16x8 af = *(const s16x8*)&BufB[wv * 16 + col][kc * 32 + kg * 8];
    #pragma unroll
    for (int ct = 0; ct < 16; ++ct) {
      s16x8 bf = *(const s16x8*)&w_1[(size_t)(ct * 16 + col) * 256 + kc * 32 + kg * 8];
      acc[ct] = __builtin_amdgcn_mfma_f32_16x16x32_bf16(af, bf, acc[ct], 0, 0, 0);
    }
  }
  __syncthreads();
  #pragma unroll
  for (int ct = 0; ct < 16; ++ct)
    #pragma unroll
    for (int i = 0; i < 4; ++i)
      BufA[wv * 16 + kg * 4 + i][ct * 16 + col] = f2b(fmaxf(acc[ct][i], 0.0f));
  __syncthreads();

  // step4: out = sigmoid(w1 . W2 + b2)
  {
    int r = tid >> 2, qq = tid & 3;
    float a = 0.0f;
    #pragma unroll
    for (int i2 = 0; i2 < 64; ++i2) {
      int k = qq * 64 + i2;
      a += b2f(BufA[r][k]) * W2[k];
    }
    a += __shfl_xor(a, 1); a += __shfl_xor(a, 2);
    if (qq == 0) out[mbase + r] = sigmoidf_(a + b2[0]);
  }
}

extern "C" void kernel_launch(void* const* d_in, const int* in_sizes, int n_in,
                              void* d_out, int out_size, void* d_ws, size_t ws_size,
                              hipStream_t stream)
{
  (void)in_sizes; (void)n_in; (void)out_size;
  const float* x    = (const float*)d_in[0];
  const float* phn  = (const float*)d_in[1];
  const float* h0i  = (const float*)d_in[2];
  const float* W_in = (const float*)d_in[3];
  const float* b_in = (const float*)d_in[4];
  const float* Wih0 = (const float*)d_in[5];
  const float* Whh0 = (const float*)d_in[6];
  const float* bih0 = (const float*)d_in[7];
  const float* bhh0 = (const float*)d_in[8];
  const float* Wih1 = (const float*)d_in[9];
  const float* Whh1 = (const float*)d_in[10];
  const float* bih1 = (const float*)d_in[11];
  const float* bhh1 = (const float*)d_in[12];
  const float* Wq = (const float*)d_in[13];
  const float* Wk = (const float*)d_in[14];
  const float* Wv = (const float*)d_in[15];
  const float* bq = (const float*)d_in[16];
  const float* bk = (const float*)d_in[17];
  const float* bv = (const float*)d_in[18];
  const float* Wo = (const float*)d_in[19];
  const float* bo = (const float*)d_in[20];
  const float* Wc = (const float*)d_in[21];
  const float* bc = (const float*)d_in[22];
  const float* W1 = (const float*)d_in[23];
  const float* b1 = (const float*)d_in[24];
  const float* W2 = (const float*)d_in[25];
  const float* b2 = (const float*)d_in[26];
  const unsigned char* amask = (const unsigned char*)d_in[27];
  float* out = (float*)d_out;

  unsigned short* ws = (unsigned short*)d_ws;
  size_t off = 0;
  unsigned short* wpk1  = ws + off; off += 196608;
  unsigned short* wpk2  = ws + off; off += 393216;
  unsigned short* w_q   = ws + off; off += 65536;
  unsigned short* w_o   = ws + off; off += 65536;
  unsigned short* w_c   = ws + off; off += 131072;
  unsigned short* w_1   = ws + off; off += 65536;
  unsigned short* k_all = ws + off; off += (size_t)B_ * N_ * 256;
  unsigned short* v_all = ws + off; off += (size_t)B_ * N_ * 256;
  unsigned short* h1_all = ws + off; off += (size_t)B_ * T_ * 256;
  unsigned short* bigR  = ws + off; off += (size_t)B_ * T_ * 768;   // gi0, later q/ctx
  unsigned short* gi0   = bigR;
  unsigned short* q_all = bigR;                                     // alias after seq3
  unsigned short* ctx_all = bigR + (size_t)B_ * T_ * 256;
  if (ws_size < off * sizeof(unsigned short)) return;

  hipLaunchKernelGGL(pack_w1, dim3(768), dim3(256), 0, stream, Whh0, wpk1);
  hipLaunchKernelGGL(pack_w2, dim3(1536), dim3(256), 0, stream, Wih1, Whh1, wpk2);
  hipLaunchKernelGGL(cvt_bf16, dim3(128), dim3(512), 0, stream, Wq, w_q, 65536);
  hipLaunchKernelGGL(cvt_bf16, dim3(128), dim3(512), 0, stream, Wo, w_o, 65536);
  hipLaunchKernelGGL(cvt_bf16, dim3(256), dim3(512), 0, stream, Wc, w_c, 131072);
  hipLaunchKernelGGL(cvt_bf16, dim3(128), dim3(512), 0, stream, W1, w_1, 65536);

  hipLaunchKernelGGL(kv_gemm, dim3(2048, 2), dim3(256), 0, stream,
                     phn, Wk, Wv, bk, bv, k_all, v_all);
  hipLaunchKernelGGL(gi0_gemm, dim3(1024, 3), dim3(256), 0, stream,
                     x, W_in, b_in, Wih0, bih0, gi0);
  hipLaunchKernelGGL(seq3_kernel, dim3(64), dim3(512), 0, stream,
                     gi0, h0i, wpk1, bhh0, wpk2, bih1, bhh1, h1_all);
  hipLaunchKernelGGL(q_gemm, dim3(1024), dim3(256), 0, stream,
                     h1_all, w_q, bq, q_all);
  hipLaunchKernelGGL(attn_kernel, dim3(1024), dim3(256), 0, stream,
                     q_all, k_all, v_all, amask, ctx_all);
  hipLaunchKernelGGL(out_chain, dim3(1024), dim3(256), 0, stream,
                     h1_all, ctx_all, w_o, bo, w_c, bc, w_1, b1, W2, b2, out);
}

// Round 6
// 4353.990 us; speedup vs baseline: 1.0865x; 1.0865x over previous
//
#include <hip/hip_runtime.h>
#include <hip/hip_bf16.h>
#include <cstddef>
#include <cstdint>

// EdgeLevelRNN: B=1024, T=64, N=128, E=H=NH=256, HEADS=4, DH=64, F=1, L=2
// Phase A: pack_all (weight convert/pack, 1 launch), kv_gemm, gi0_gemm.
// Phase B (serial): seq4_kernel, 64 blocks x 512 thr, 16 batches/block.
//   __launch_bounds__(512,2) -> 256 VGPR budget so the 16-slot / 12-ahead
//   register weight pipeline survives regalloc (R3 failed: 128 VGPRs
//   collapsed load->use distance to ~1, full ~900cy latency per load).
// Phase C (parallel): q GEMM, attention, fused Wo/Wc/W1/W2 chain.
// (Second resubmission — R4 and R5 both hit GPUAcquisitionTimeout, no data.)

#define B_  1024
#define T_  64
#define N_  128

typedef __attribute__((ext_vector_type(8))) short s16x8;
typedef __attribute__((ext_vector_type(4))) float f32x4;

__device__ __forceinline__ unsigned short f2b(float f) {
  unsigned int u = __float_as_uint(f);
  u += 0x7FFFu + ((u >> 16) & 1u);          // RNE
  return (unsigned short)(u >> 16);
}
__device__ __forceinline__ float b2f(unsigned short s){ return __uint_as_float(((unsigned int)s) << 16); }
__device__ __forceinline__ float sigmoidf_(float x){ return 1.0f / (1.0f + __expf(-x)); }
__device__ __forceinline__ float tanhf_(float x){
  float t = __expf(-2.0f * fabsf(x));
  float r = (1.0f - t) / (1.0f + t);
  return x >= 0.0f ? r : -r;
}
__device__ __forceinline__ void gld_lds16(const void* g, void* l) {
  __builtin_amdgcn_global_load_lds(
      (const __attribute__((address_space(1))) void*)g,
      (__attribute__((address_space(3))) void*)l, 16, 0, 0);
}

// ---- one merged pack/convert kernel (6 segments, 1 launch) ----
// seg0 pack Whh0 -> wpk1 [w][6][8][512]     (196608, blocks 0..767)
// seg1 pack Wih1/Whh1 -> wpk2 [w][12][8][512] (393216, blocks 768..2303)
// seg2..5 cvt Wq,Wo,Wc,W1                    (blocks 2304..3583)
__global__ __launch_bounds__(256) void pack_all(
    const float* __restrict__ Whh0, const float* __restrict__ Wih1,
    const float* __restrict__ Whh1, const float* __restrict__ Wq,
    const float* __restrict__ Wo, const float* __restrict__ Wc,
    const float* __restrict__ W1,
    unsigned short* __restrict__ wpk1, unsigned short* __restrict__ wpk2,
    unsigned short* __restrict__ w_q, unsigned short* __restrict__ w_o,
    unsigned short* __restrict__ w_c, unsigned short* __restrict__ w_1)
{
  const int blk = blockIdx.x, tid = threadIdx.x;
  if (blk < 768) {
    int d = blk * 256 + tid;                 // 196608
    int e = d & 7, l = (d >> 3) & 63, bb = d >> 9;
    int kc = bb & 7, tj = bb >> 3;
    int j = tj % 6, w = tj / 6;
    int row = (j >> 1) * 256 + w * 32 + (j & 1) * 16 + (l & 15);
    int colk = kc * 32 + (l >> 4) * 8 + e;
    wpk1[d] = f2b(Whh0[(size_t)row * 256 + colk]);
  } else if (blk < 2304) {
    int d = (blk - 768) * 256 + tid;         // 393216
    int e = d & 7, l = (d >> 3) & 63, bb = d >> 9;
    int kc = bb & 7, tj = bb >> 3;
    int j = tj % 12, w = tj / 12;
    int jj = (j < 6) ? j : j - 6;
    int row = (jj >> 1) * 256 + w * 32 + (jj & 1) * 16 + (l & 15);
    int colk = kc * 32 + (l >> 4) * 8 + e;
    const float* src = (j < 6) ? Wih1 : Whh1;
    wpk2[d] = f2b(src[(size_t)row * 256 + colk]);
  } else if (blk < 2560) {
    int d = (blk - 2304) * 256 + tid; w_q[d] = f2b(Wq[d]);
  } else if (blk < 2816) {
    int d = (blk - 2560) * 256 + tid; w_o[d] = f2b(Wo[d]);
  } else if (blk < 3328) {
    int d = (blk - 2816) * 256 + tid; w_c[d] = f2b(Wc[d]);
  } else {
    int d = (blk - 3328) * 256 + tid; w_1[d] = f2b(W1[d]);
  }
}

#define LDA 264   // 256 + 8 pad (bf16 elems)
#define LDB 40    // 32 + 8 pad

// PK1: C[m, 0:512] = phn[m,:] @ [Wk;Wv]^T + [bk;bv]; split to k_all / v_all (bf16)
__global__ __launch_bounds__(256) void kv_gemm(
    const float* __restrict__ phn,
    const float* __restrict__ Wk, const float* __restrict__ Wv,
    const float* __restrict__ bk, const float* __restrict__ bv,
    unsigned short* __restrict__ k_all, unsigned short* __restrict__ v_all)
{
  __shared__ __align__(16) unsigned short Alds[64 * LDA];
  __shared__ __align__(16) unsigned short Blds[256 * LDB];
  const int tid = threadIdx.x;
  const int m0 = blockIdx.x * 64;
  const int n0 = blockIdx.y * 256;
  #pragma unroll
  for (int p = 0; p < 16; ++p) {
    int q = p * 256 + tid;
    int row = q >> 6, kq = q & 63;
    float4 f = *(const float4*)&phn[(size_t)(m0 + row) * 256 + (size_t)kq * 4];
    ushort4 h; h.x = f2b(f.x); h.y = f2b(f.y); h.z = f2b(f.z); h.w = f2b(f.w);
    *(ushort4*)&Alds[row * LDA + kq * 4] = h;
  }
  const int wave = tid >> 6, lane = tid & 63;
  const int lr = lane & 15, lk = (lane >> 4) * 8;
  f32x4 acc[16];
  #pragma unroll
  for (int t = 0; t < 16; ++t) {
    int j = n0 + t * 16 + lr;
    float bz = (j < 256) ? bk[j] : bv[j - 256];
    acc[t][0] = bz; acc[t][1] = bz; acc[t][2] = bz; acc[t][3] = bz;
  }
  for (int kc = 0; kc < 8; ++kc) {
    __syncthreads();
    #pragma unroll
    for (int p = 0; p < 8; ++p) {
      int j = p * 32 + (tid >> 3);
      int jg = n0 + j;
      const float* wrow = (jg < 256) ? &Wk[(size_t)jg * 256] : &Wv[(size_t)(jg - 256) * 256];
      float4 f = *(const float4*)&wrow[kc * 32 + (tid & 7) * 4];
      ushort4 h; h.x = f2b(f.x); h.y = f2b(f.y); h.z = f2b(f.z); h.w = f2b(f.w);
      *(ushort4*)&Blds[j * LDB + (tid & 7) * 4] = h;
    }
    __syncthreads();
    s16x8 a = *(const s16x8*)&Alds[(wave * 16 + lr) * LDA + kc * 32 + lk];
    #pragma unroll
    for (int t = 0; t < 16; ++t) {
      s16x8 b = *(const s16x8*)&Blds[(t * 16 + lr) * LDB + lk];
      acc[t] = __builtin_amdgcn_mfma_f32_16x16x32_bf16(a, b, acc[t], 0, 0, 0);
    }
  }
  const int rbase = m0 + wave * 16 + (lane >> 4) * 4;
  #pragma unroll
  for (int t = 0; t < 16; ++t) {
    int j = n0 + t * 16 + lr;
    #pragma unroll
    for (int i = 0; i < 4; ++i) {
      size_t m = (size_t)(rbase + i);
      unsigned short hv = f2b(acc[t][i]);
      if (j < 256) k_all[m * 256 + j] = hv;
      else         v_all[m * 256 + (j - 256)] = hv;
    }
  }
}

// PK2: gi0[t][b][f0:f0+256] = relu(x[m]*W_in + b_in) @ Wih0^T + bih0 (bf16)
__global__ __launch_bounds__(256) void gi0_gemm(
    const float* __restrict__ x, const float* __restrict__ W_in, const float* __restrict__ b_in,
    const float* __restrict__ Wih0, const float* __restrict__ bih0,
    unsigned short* __restrict__ gi0)
{
  __shared__ __align__(16) unsigned short Alds[64 * LDA];
  __shared__ __align__(16) unsigned short Blds[256 * LDB];
  const int tid = threadIdx.x;
  const int m0 = blockIdx.x * 64;
  const int f0 = blockIdx.y * 256;
  float win = W_in[tid], bin = b_in[tid];
  for (int p = 0; p < 64; ++p) {
    float e = fmaxf(fmaf(x[m0 + p], win, bin), 0.0f);
    Alds[p * LDA + tid] = f2b(e);
  }
  const int wave = tid >> 6, lane = tid & 63;
  const int lr = lane & 15, lk = (lane >> 4) * 8;
  f32x4 acc[16];
  #pragma unroll
  for (int t = 0; t < 16; ++t) {
    float bz = bih0[f0 + t * 16 + lr];
    acc[t][0] = bz; acc[t][1] = bz; acc[t][2] = bz; acc[t][3] = bz;
  }
  for (int kc = 0; kc < 8; ++kc) {
    __syncthreads();
    #pragma unroll
    for (int p = 0; p < 8; ++p) {
      int j = p * 32 + (tid >> 3);
      const float* wrow = &Wih0[(size_t)(f0 + j) * 256];
      float4 f = *(const float4*)&wrow[kc * 32 + (tid & 7) * 4];
      ushort4 h; h.x = f2b(f.x); h.y = f2b(f.y); h.z = f2b(f.z); h.w = f2b(f.w);
      *(ushort4*)&Blds[j * LDB + (tid & 7) * 4] = h;
    }
    __syncthreads();
    s16x8 a = *(const s16x8*)&Alds[(wave * 16 + lr) * LDA + kc * 32 + lk];
    #pragma unroll
    for (int t = 0; t < 16; ++t) {
      s16x8 b = *(const s16x8*)&Blds[(t * 16 + lr) * LDB + lk];
      acc[t] = __builtin_amdgcn_mfma_f32_16x16x32_bf16(a, b, acc[t], 0, 0, 0);
    }
  }
  const int rbase = m0 + wave * 16 + (lane >> 4) * 4;
  #pragma unroll
  for (int t = 0; t < 16; ++t) {
    int f = f0 + t * 16 + lr;
    #pragma unroll
    for (int i = 0; i < 4; ++i) {
      int m = rbase + i;                       // m = b*64 + t
      gi0[((size_t)(m & 63) * 1024 + (m >> 6)) * 768 + f] = f2b(acc[t][i]);
    }
  }
}

// ---------------- Phase B: sequential GRU core, weights -> VGPR stream ----------------
__global__ __launch_bounds__(512, 2) void seq4_kernel(
    const unsigned short* __restrict__ gi0,     // [T][B][768]
    const float* __restrict__ h0_init,          // [2][B][256]
    const unsigned short* __restrict__ wpk1,    // [w][6][8][512]
    const float* __restrict__ bhh0,
    const unsigned short* __restrict__ wpk2,    // [w][12][8][512]
    const float* __restrict__ bih1, const float* __restrict__ bhh1,
    unsigned short* __restrict__ h1_all)        // [B][T][256]
{
  __shared__ __align__(16) unsigned short h0b[16][264];
  __shared__ __align__(16) unsigned short h1b[16][264];
  __shared__ __align__(16) unsigned short gi0s[16 * 768];   // 24KB, linear (DMA dest)

  const int tid = threadIdx.x;
  const int w = tid >> 6, lane = tid & 63;
  const int col = lane & 15, kg = lane >> 4;
  const int b0 = blockIdx.x * 16;

  // init state: lane owns (batch kg*4+i, feature w*32+sub*16+col)
  float hp0[8], hp1[8];
  #pragma unroll
  for (int sub = 0; sub < 2; ++sub)
    #pragma unroll
    for (int i = 0; i < 4; ++i) {
      int bt = kg * 4 + i, fl = w * 32 + sub * 16 + col;
      float v0 = h0_init[(size_t)(b0 + bt) * 256 + fl];
      float v1 = h0_init[(size_t)(B_ * 256) + (size_t)(b0 + bt) * 256 + fl];
      hp0[sub * 4 + i] = v0; hp1[sub * 4 + i] = v1;
      h0b[bt][fl] = f2b(v0); h1b[bt][fl] = f2b(v1);
    }
  float bb0[6], bb1[12];
  #pragma unroll
  for (int j = 0; j < 6; ++j) {
    int f = (j >> 1) * 256 + w * 32 + (j & 1) * 16 + col;
    bb0[j] = bhh0[f];
    bb1[j] = bih1[f];
    bb1[6 + j] = bhh1[f];
  }
  __syncthreads();

  const unsigned short* w1base = wpk1 + (size_t)w * 24576 + (size_t)lane * 8;
  const unsigned short* w2base = wpk2 + (size_t)w * 49152 + (size_t)lane * 8;

  s16x8 Wr[16];

  #pragma unroll 1
  for (int t = 0; t < T_; ++t) {
    // --- stage gi0 tile (16 rows x 768) into LDS via DMA: 3 chunks/wave ---
    {
      const unsigned short* gsrc = gi0 + ((size_t)t * 1024 + b0) * 768;
      #pragma unroll
      for (int c = 0; c < 3; ++c)
        gld_lds16(gsrc + (size_t)(w * 3 + c) * 512 + (size_t)lane * 8,
                  &gi0s[(w * 3 + c) * 512]);
    }
    __builtin_amdgcn_sched_barrier(0);
    // S1 weight prologue (12 ahead)
    #pragma unroll
    for (int p = 0; p < 12; ++p)
      Wr[p] = *(const s16x8*)(w1base + (size_t)p * 512);
    // A-frags (old state) — must be read by ALL waves before anyone rewrites
    s16x8 h0o[8], h1o[8];
    #pragma unroll
    for (int kc = 0; kc < 8; ++kc) {
      h0o[kc] = *(const s16x8*)&h0b[col][kc * 32 + kg * 8];
      h1o[kc] = *(const s16x8*)&h1b[col][kc * 32 + kg * 8];
    }
    // wait for this wave's gi0 DMA (3 oldest vmem ops; 12 prefetch may fly)
    asm volatile("s_waitcnt vmcnt(12)" ::: "memory");
    __syncthreads();                                   // (a)

    // ---- S1: gh0 = h0 @ Whh0^T + bhh0 (48 MFMA), fused GRU0 ----
    f32x4 acc[6];
    #pragma unroll
    for (int j = 0; j < 6; ++j) { float bz = bb0[j]; acc[j][0]=bz; acc[j][1]=bz; acc[j][2]=bz; acc[j][3]=bz; }
    #pragma unroll
    for (int j = 0; j < 6; ++j) {
      #pragma unroll
      for (int kc = 0; kc < 8; ++kc) {
        const int g = j * 8 + kc;
        if (g + 12 < 48) Wr[(g + 12) & 15] = *(const s16x8*)(w1base + (size_t)(g + 12) * 512);
        else             Wr[(g + 12) & 15] = *(const s16x8*)(w2base + (size_t)(g + 12 - 48) * 512);
        acc[j] = __builtin_amdgcn_mfma_f32_16x16x32_bf16(h0o[kc], Wr[g & 15], acc[j], 0, 0, 0);
      }
    }
    // GRU0 elementwise (all 512 lanes, 8 outputs each)
    #pragma unroll
    for (int sub = 0; sub < 2; ++sub) {
      const int fl = w * 32 + sub * 16 + col;
      #pragma unroll
      for (int i = 0; i < 4; ++i) {
        const int bt = kg * 4 + i;
        float ir  = b2f(gi0s[bt * 768 + fl]);
        float iz  = b2f(gi0s[bt * 768 + 256 + fl]);
        float in_ = b2f(gi0s[bt * 768 + 512 + fl]);
        float r = sigmoidf_(ir + acc[0 + sub][i]);
        float z = sigmoidf_(iz + acc[2 + sub][i]);
        float n = tanhf_(in_ + r * acc[4 + sub][i]);
        float hn = (1.0f - z) * n + z * hp0[sub * 4 + i];
        hp0[sub * 4 + i] = hn;
        h0b[bt][fl] = f2b(hn);
      }
    }
    __syncthreads();                                   // (b)

    // ---- S2: gi1 = h0n @ Wih1^T ; gh1 = h1 @ Whh1^T (96 MFMA), fused GRU1 ----
    s16x8 h0n[8];
    #pragma unroll
    for (int kc = 0; kc < 8; ++kc)
      h0n[kc] = *(const s16x8*)&h0b[col][kc * 32 + kg * 8];
    f32x4 acc2[12];
    #pragma unroll
    for (int j = 0; j < 12; ++j) { float bz = bb1[j]; acc2[j][0]=bz; acc2[j][1]=bz; acc2[j][2]=bz; acc2[j][3]=bz; }
    #pragma unroll
    for (int j = 0; j < 12; ++j) {
      #pragma unroll
      for (int kc = 0; kc < 8; ++kc) {
        const int g = 48 + j * 8 + kc;
        if (g + 12 < 144) Wr[(g + 12) & 15] = *(const s16x8*)(w2base + (size_t)(g + 12 - 48) * 512);
        s16x8 af = (j < 6) ? h0n[kc] : h1o[kc];
        acc2[j] = __builtin_amdgcn_mfma_f32_16x16x32_bf16(af, Wr[g & 15], acc2[j], 0, 0, 0);
      }
    }
    // GRU1 elementwise
    #pragma unroll
    for (int sub = 0; sub < 2; ++sub) {
      const int fl = w * 32 + sub * 16 + col;
      #pragma unroll
      for (int i = 0; i < 4; ++i) {
        const int bt = kg * 4 + i;
        float r = sigmoidf_(acc2[0 + sub][i] + acc2[6 + sub][i]);
        float z = sigmoidf_(acc2[2 + sub][i] + acc2[8 + sub][i]);
        float n = tanhf_(acc2[4 + sub][i] + r * acc2[10 + sub][i]);
        float hn = (1.0f - z) * n + z * hp1[sub * 4 + i];
        hp1[sub * 4 + i] = hn;
        h1b[bt][fl] = f2b(hn);
      }
    }
    __syncthreads();                                   // (c)

    // h1b -> h1_all, coalesced: wave w stores rows 2w, 2w+1 (512B each)
    {
      const int row = 2 * w + (lane >> 5), c16 = lane & 31;
      s16x8 vv = *(const s16x8*)&h1b[row][c16 * 8];
      *(s16x8*)&h1_all[((size_t)(b0 + row) * T_ + t) * 256 + c16 * 8] = vv;
    }
  }
}

// ---------------- Phase C ----------------
// C1: q_all = (h1_all @ Wq^T + bq) * 0.125   (bf16)
__global__ __launch_bounds__(256) void q_gemm(
    const unsigned short* __restrict__ h1_all,
    const unsigned short* __restrict__ w_q, const float* __restrict__ bq,
    unsigned short* __restrict__ q_all)
{
  __shared__ __align__(16) unsigned short A[64][264];
  const int tid = threadIdx.x;
  const int m0 = blockIdx.x * 64;
  #pragma unroll
  for (int p = 0; p < 8; ++p) {
    int idx = p * 256 + tid;
    int row = idx >> 5, c8 = idx & 31;
    *(uint4*)&A[row][c8 * 8] = *(const uint4*)&h1_all[(size_t)(m0 + row) * 256 + c8 * 8];
  }
  __syncthreads();
  const int wv = tid >> 6, lane = tid & 63;
  const int col = lane & 15, kg = lane >> 4;
  f32x4 acc[16];
  #pragma unroll
  for (int ct = 0; ct < 16; ++ct) {
    float bz = bq[ct * 16 + col];
    acc[ct][0]=bz; acc[ct][1]=bz; acc[ct][2]=bz; acc[ct][3]=bz;
  }
  #pragma unroll
  for (int kc = 0; kc < 8; ++kc) {
    s16x8 af = *(const s16x8*)&A[wv * 16 + col][kc * 32 + kg * 8];
    #pragma unroll
    for (int ct = 0; ct < 16; ++ct) {
      s16x8 bf = *(const s16x8*)&w_q[(size_t)(ct * 16 + col) * 256 + kc * 32 + kg * 8];
      acc[ct] = __builtin_amdgcn_mfma_f32_16x16x32_bf16(af, bf, acc[ct], 0, 0, 0);
    }
  }
  const int r0 = m0 + wv * 16 + kg * 4;
  #pragma unroll
  for (int ct = 0; ct < 16; ++ct) {
    int j = ct * 16 + col;
    #pragma unroll
    for (int i = 0; i < 4; ++i)
      q_all[(size_t)(r0 + i) * 256 + j] = f2b(acc[ct][i] * 0.125f);
  }
}

// C2: attention per (b): scores = q.k, softmax(+mask), ctx = a.v  -> ctx_all
__global__ __launch_bounds__(256) void attn_kernel(
    const unsigned short* __restrict__ q_all,
    const unsigned short* __restrict__ k_all,
    const unsigned short* __restrict__ v_all,
    const unsigned char* __restrict__ amask,
    unsigned short* __restrict__ ctx_all)
{
  __shared__ __align__(16) unsigned short qh[64][72];
  __shared__ __align__(16) unsigned short kh[128][72];
  __shared__ __align__(16) unsigned short vT[64][136];
  __shared__ __align__(16) unsigned short P[64][136];
  const int b = blockIdx.x;
  const int tid = threadIdx.x;
  const int wv = tid >> 6, lane = tid & 63;
  const int col = lane & 15, kg = lane >> 4;
  bool mk[8];
  #pragma unroll
  for (int nt = 0; nt < 8; ++nt) mk[nt] = amask[(size_t)b * 128 + nt * 16 + col] != 0;

  #pragma unroll 1
  for (int h = 0; h < 4; ++h) {
    #pragma unroll
    for (int p = 0; p < 2; ++p) {
      int idx = p * 256 + tid, row = idx >> 3, c8 = idx & 7;
      *(uint4*)&qh[row][c8 * 8] = *(const uint4*)&q_all[((size_t)b * 64 + row) * 256 + h * 64 + c8 * 8];
    }
    #pragma unroll
    for (int p = 0; p < 4; ++p) {
      int idx = p * 256 + tid, row = idx >> 3, c8 = idx & 7;
      *(uint4*)&kh[row][c8 * 8] = *(const uint4*)&k_all[((size_t)b * 128 + row) * 256 + h * 64 + c8 * 8];
    }
    #pragma unroll
    for (int rep = 0; rep < 32; ++rep) {
      int e = rep * 256 + tid;
      int n = e >> 6, d = e & 63;
      vT[d][n] = v_all[((size_t)b * 128 + n) * 256 + h * 64 + d];
    }
    __syncthreads();

    s16x8 aq0 = *(const s16x8*)&qh[wv * 16 + col][kg * 8];
    s16x8 aq1 = *(const s16x8*)&qh[wv * 16 + col][32 + kg * 8];
    f32x4 s[8];
    #pragma unroll
    for (int nt = 0; nt < 8; ++nt) {
      f32x4 z = {0.f, 0.f, 0.f, 0.f};
      s16x8 bk0 = *(const s16x8*)&kh[nt * 16 + col][kg * 8];
      s16x8 bk1 = *(const s16x8*)&kh[nt * 16 + col][32 + kg * 8];
      z = __builtin_amdgcn_mfma_f32_16x16x32_bf16(aq0, bk0, z, 0, 0, 0);
      z = __builtin_amdgcn_mfma_f32_16x16x32_bf16(aq1, bk1, z, 0, 0, 0);
      s[nt] = z;
    }
    #pragma unroll
    for (int nt = 0; nt < 8; ++nt)
      if (mk[nt]) { s[nt][0] = -1e9f; s[nt][1] = -1e9f; s[nt][2] = -1e9f; s[nt][3] = -1e9f; }
    f32x4 mx = s[0];
    #pragma unroll
    for (int nt = 1; nt < 8; ++nt)
      #pragma unroll
      for (int i = 0; i < 4; ++i) mx[i] = fmaxf(mx[i], s[nt][i]);
    #pragma unroll
    for (int i = 0; i < 4; ++i) {
      float m = mx[i];
      m = fmaxf(m, __shfl_xor(m, 1)); m = fmaxf(m, __shfl_xor(m, 2));
      m = fmaxf(m, __shfl_xor(m, 4)); m = fmaxf(m, __shfl_xor(m, 8));
      mx[i] = m;
    }
    f32x4 sm = {0.f, 0.f, 0.f, 0.f};
    #pragma unroll
    for (int nt = 0; nt < 8; ++nt)
      #pragma unroll
      for (int i = 0; i < 4; ++i) { s[nt][i] = __expf(s[nt][i] - mx[i]); sm[i] += s[nt][i]; }
    #pragma unroll
    for (int i = 0; i < 4; ++i) {
      float t2 = sm[i];
      t2 += __shfl_xor(t2, 1); t2 += __shfl_xor(t2, 2);
      t2 += __shfl_xor(t2, 4); t2 += __shfl_xor(t2, 8);
      sm[i] = 1.0f / t2;
    }
    #pragma unroll
    for (int nt = 0; nt < 8; ++nt)
      #pragma unroll
      for (int i = 0; i < 4; ++i)
        P[wv * 16 + kg * 4 + i][nt * 16 + col] = f2b(s[nt][i] * sm[i]);
    __syncthreads();

    f32x4 c4[4];
    #pragma unroll
    for (int dt = 0; dt < 4; ++dt) { c4[dt][0]=0.f; c4[dt][1]=0.f; c4[dt][2]=0.f; c4[dt][3]=0.f; }
    #pragma unroll
    for (int kc = 0; kc < 4; ++kc) {
      s16x8 ap = *(const s16x8*)&P[wv * 16 + col][kc * 32 + kg * 8];
      #pragma unroll
      for (int dt = 0; dt < 4; ++dt) {
        s16x8 bv_ = *(const s16x8*)&vT[dt * 16 + col][kc * 32 + kg * 8];
        c4[dt] = __builtin_amdgcn_mfma_f32_16x16x32_bf16(ap, bv_, c4[dt], 0, 0, 0);
      }
    }
    #pragma unroll
    for (int dt = 0; dt < 4; ++dt) {
      int d = h * 64 + dt * 16 + col;
      #pragma unroll
      for (int i = 0; i < 4; ++i)
        ctx_all[((size_t)b * 64 + wv * 16 + kg * 4 + i) * 256 + d] = f2b(c4[dt][i]);
    }
    __syncthreads();
  }
}

// C3: o = ctx@Wo^T+bo; comb = relu([h1,o]@Wc^T+bc); w1 = relu(comb@W1^T+b1);
//     out = sigmoid(w1.W2 + b2)
__global__ __launch_bounds__(256) void out_chain(
    const unsigned short* __restrict__ h1_all,
    const unsigned short* __restrict__ ctx_all,
    const unsigned short* __restrict__ w_o, const float* __restrict__ bo,
    const unsigned short* __restrict__ w_c, const float* __restrict__ bc,
    const unsigned short* __restrict__ w_1, const float* __restrict__ b1,
    const float* __restrict__ W2, const float* __restrict__ b2,
    float* __restrict__ out)
{
  __shared__ __align__(16) unsigned short BufA[64][264];
  __shared__ __align__(16) unsigned short BufB[64][264];
  const int b = blockIdx.x;
  const int tid = threadIdx.x;
  const int wv = tid >> 6, lane = tid & 63;
  const int col = lane & 15, kg = lane >> 4;
  const size_t mbase = (size_t)b * 64;
  #pragma unroll
  for (int p = 0; p < 8; ++p) {
    int idx = p * 256 + tid, row = idx >> 5, c8 = idx & 31;
    *(uint4*)&BufA[row][c8 * 8] = *(const uint4*)&h1_all[(mbase + row) * 256 + c8 * 8];
    *(uint4*)&BufB[row][c8 * 8] = *(const uint4*)&ctx_all[(mbase + row) * 256 + c8 * 8];
  }
  __syncthreads();
  f32x4 acc[16];

  // step1: o = ctx @ Wo^T + bo
  #pragma unroll
  for (int ct = 0; ct < 16; ++ct) { float bz = bo[ct*16+col]; acc[ct][0]=bz; acc[ct][1]=bz; acc[ct][2]=bz; acc[ct][3]=bz; }
  #pragma unroll
  for (int kc = 0; kc < 8; ++kc) {
    s16x8 af = *(const s16x8*)&BufB[wv * 16 + col][kc * 32 + kg * 8];
    #pragma unroll
    for (int ct = 0; ct < 16; ++ct) {
      s16x8 bf = *(const s16x8*)&w_o[(size_t)(ct * 16 + col) * 256 + kc * 32 + kg * 8];
      acc[ct] = __builtin_amdgcn_mfma_f32_16x16x32_bf16(af, bf, acc[ct], 0, 0, 0);
    }
  }
  __syncthreads();
  #pragma unroll
  for (int ct = 0; ct < 16; ++ct)
    #pragma unroll
    for (int i = 0; i < 4; ++i)
      BufB[wv * 16 + kg * 4 + i][ct * 16 + col] = f2b(acc[ct][i]);
  __syncthreads();

  // step2: comb = relu(h1@Wc[:,:256]^T + o@Wc[:,256:]^T + bc)
  #pragma unroll
  for (int ct = 0; ct < 16; ++ct) { float bz = bc[ct*16+col]; acc[ct][0]=bz; acc[ct][1]=bz; acc[ct][2]=bz; acc[ct][3]=bz; }
  #pragma unroll
  for (int kc = 0; kc < 16; ++kc) {
    s16x8 af;
    if (kc < 8) af = *(const s16x8*)&BufA[wv * 16 + col][kc * 32 + kg * 8];
    else        af = *(const s16x8*)&BufB[wv * 16 + col][(kc - 8) * 32 + kg * 8];
    #pragma unroll
    for (int ct = 0; ct < 16; ++ct) {
      s16x8 bf = *(const s16x8*)&w_c[(size_t)(ct * 16 + col) * 512 + kc * 32 + kg * 8];
      acc[ct] = __builtin_amdgcn_mfma_f32_16x16x32_bf16(af, bf, acc[ct], 0, 0, 0);
    }
  }
  __syncthreads();
  #pragma unroll
  for (int ct = 0; ct < 16; ++ct)
    #pragma unroll
    for (int i = 0; i < 4; ++i)
      BufB[wv * 16 + kg * 4 + i][ct * 16 + col] = f2b(fmaxf(acc[ct][i], 0.0f));
  __syncthreads();

  // step3: w1 = relu(comb @ W1^T + b1)
  #pragma unroll
  for (int ct = 0; ct < 16; ++ct) { float bz = b1[ct*16+col]; acc[ct][0]=bz; acc[ct][1]=bz; acc[ct][2]=bz; acc[ct][3]=bz; }
  #pragma unroll
  for (int kc = 0; kc < 8; ++kc) {
    s16x8 af = *(const s16x8*)&BufB[wv * 16 + col][kc * 32 + kg * 8];
    #pragma unroll
    for (int ct = 0; ct < 16; ++ct) {
      s16x8 bf = *(const s16x8*)&w_1[(size_t)(ct * 16 + col) * 256 + kc * 32 + kg * 8];
      acc[ct] = __builtin_amdgcn_mfma_f32_16x16x32_bf16(af, bf, acc[ct], 0, 0, 0);
    }
  }
  __syncthreads();
  #pragma unroll
  for (int ct = 0; ct < 16; ++ct)
    #pragma unroll
    for (int i = 0; i < 4; ++i)
      BufA[wv * 16 + kg * 4 + i][ct * 16 + col] = f2b(fmaxf(acc[ct][i], 0.0f));
  __syncthreads();

  // step4: out = sigmoid(w1 . W2 + b2)
  {
    int r = tid >> 2, qq = tid & 3;
    float a = 0.0f;
    #pragma unroll
    for (int i2 = 0; i2 < 64; ++i2) {
      int k = qq * 64 + i2;
      a += b2f(BufA[r][k]) * W2[k];
    }
    a += __shfl_xor(a, 1); a += __shfl_xor(a, 2);
    if (qq == 0) out[mbase + r] = sigmoidf_(a + b2[0]);
  }
}

extern "C" void kernel_launch(void* const* d_in, const int* in_sizes, int n_in,
                              void* d_out, int out_size, void* d_ws, size_t ws_size,
                              hipStream_t stream)
{
  (void)in_sizes; (void)n_in; (void)out_size;
  const float* x    = (const float*)d_in[0];
  const float* phn  = (const float*)d_in[1];
  const float* h0i  = (const float*)d_in[2];
  const float* W_in = (const float*)d_in[3];
  const float* b_in = (const float*)d_in[4];
  const float* Wih0 = (const float*)d_in[5];
  const float* Whh0 = (const float*)d_in[6];
  const float* bih0 = (const float*)d_in[7];
  const float* bhh0 = (const float*)d_in[8];
  const float* Wih1 = (const float*)d_in[9];
  const float* Whh1 = (const float*)d_in[10];
  const float* bih1 = (const float*)d_in[11];
  const float* bhh1 = (const float*)d_in[12];
  const float* Wq = (const float*)d_in[13];
  const float* Wk = (const float*)d_in[14];
  const float* Wv = (const float*)d_in[15];
  const float* bq = (const float*)d_in[16];
  const float* bk = (const float*)d_in[17];
  const float* bv = (const float*)d_in[18];
  const float* Wo = (const float*)d_in[19];
  const float* bo = (const float*)d_in[20];
  const float* Wc = (const float*)d_in[21];
  const float* bc = (const float*)d_in[22];
  const float* W1 = (const float*)d_in[23];
  const float* b1 = (const float*)d_in[24];
  const float* W2 = (const float*)d_in[25];
  const float* b2 = (const float*)d_in[26];
  const unsigned char* amask = (const unsigned char*)d_in[27];
  float* out = (float*)d_out;

  unsigned short* ws = (unsigned short*)d_ws;
  size_t off = 0;
  unsigned short* wpk1  = ws + off; off += 196608;
  unsigned short* wpk2  = ws + off; off += 393216;
  unsigned short* w_q   = ws + off; off += 65536;
  unsigned short* w_o   = ws + off; off += 65536;
  unsigned short* w_c   = ws + off; off += 131072;
  unsigned short* w_1   = ws + off; off += 65536;
  unsigned short* k_all = ws + off; off += (size_t)B_ * N_ * 256;
  unsigned short* v_all = ws + off; off += (size_t)B_ * N_ * 256;
  unsigned short* h1_all = ws + off; off += (size_t)B_ * T_ * 256;
  unsigned short* bigR  = ws + off; off += (size_t)B_ * T_ * 768;   // gi0, later q/ctx
  unsigned short* gi0   = bigR;
  unsigned short* q_all = bigR;                                     // alias after seq4
  unsigned short* ctx_all = bigR + (size_t)B_ * T_ * 256;
  if (ws_size < off * sizeof(unsigned short)) return;

  hipLaunchKernelGGL(pack_all, dim3(3584), dim3(256), 0, stream,
                     Whh0, Wih1, Whh1, Wq, Wo, Wc, W1,
                     wpk1, wpk2, w_q, w_o, w_c, w_1);
  hipLaunchKernelGGL(kv_gemm, dim3(2048, 2), dim3(256), 0, stream,
                     phn, Wk, Wv, bk, bv, k_all, v_all);
  hipLaunchKernelGGL(gi0_gemm, dim3(1024, 3), dim3(256), 0, stream,
                     x, W_in, b_in, Wih0, bih0, gi0);
  hipLaunchKernelGGL(seq4_kernel, dim3(64), dim3(512), 0, stream,
                     gi0, h0i, wpk1, bhh0, wpk2, bih1, bhh1, h1_all);
  hipLaunchKernelGGL(q_gemm, dim3(1024), dim3(256), 0, stream,
                     h1_all, w_q, bq, q_all);
  hipLaunchKernelGGL(attn_kernel, dim3(1024), dim3(256), 0, stream,
                     q_all, k_all, v_all, amask, ctx_all);
  hipLaunchKernelGGL(out_chain, dim3(1024), dim3(256), 0, stream,
                     h1_all, ctx_all, w_o, bo, w_c, bc, w_1, b1, W2, b2, out);
}